// Round 2
// baseline (330.623 us; speedup 1.0000x reference)
//
#include <hip/hip_runtime.h>

// MLA forward: out = softmax_causal( rope(x@Wq) @ rope(x@Wk)^T / sqrt(192) ) @ (x@Wv) @ Wo + bo
// bf16 MFMA everywhere (threshold is 2% of max|ref|), fp32 accumulation.
// R2: attn = barrier-free, V^T pre-transposed in global, XCD-locality grid mapping on attn+GEMMs.

typedef __bf16 bf16;
typedef __bf16 bf16x8 __attribute__((ext_vector_type(8)));
typedef __bf16 bf16x4 __attribute__((ext_vector_type(4)));
typedef float  f32x4  __attribute__((ext_vector_type(4)));

#define DEVI __device__ __forceinline__

static constexpr int Bc = 2, Sc = 1024, DIMc = 2048, Hc = 16;
static constexpr int NOPEc = 128, QKDc = 192, VDc = 128;
static constexpr int NQ    = Hc * QKDc;        // 3072
static constexpr int NCAT  = NQ + NQ + Hc*VDc; // 8192  [Q | K | V] per row

// ---------------- fp32 -> bf16 convert (vectorized) ----------------
__global__ __launch_bounds__(256) void k_cvt(const float* __restrict__ in, bf16* __restrict__ out) {
    int i = (blockIdx.x * 256 + threadIdx.x) * 8;
    float4 a = *(const float4*)(in + i);
    float4 b = *(const float4*)(in + i + 4);
    bf16x8 o;
    o[0]=(bf16)a.x; o[1]=(bf16)a.y; o[2]=(bf16)a.z; o[3]=(bf16)a.w;
    o[4]=(bf16)b.x; o[5]=(bf16)b.y; o[6]=(bf16)b.z; o[7]=(bf16)b.w;
    *(bf16x8*)(out + i) = o;
}

// ---------------- transpose + convert: in (K x N) fp32 -> out (N x K=2048) bf16 ----------------
__global__ __launch_bounds__(256) void k_transpose(const float* __restrict__ in, bf16* __restrict__ out, int N) {
    __shared__ float tile[64][68];
    int k0 = blockIdx.x * 64, n0 = blockIdx.y * 64;
    int tr = threadIdx.x >> 4, tc = (threadIdx.x & 15) * 4;
#pragma unroll
    for (int i = 0; i < 4; i++) {
        int r = tr + i * 16;
        float4 v = *(const float4*)(in + (size_t)(k0 + r) * N + n0 + tc);
        tile[r][tc+0] = v.x; tile[r][tc+1] = v.y; tile[r][tc+2] = v.z; tile[r][tc+3] = v.w;
    }
    __syncthreads();
#pragma unroll
    for (int i = 0; i < 4; i++) {
        int n = tr + i * 16;
        bf16x4 o;
#pragma unroll
        for (int j = 0; j < 4; j++) o[j] = (bf16)tile[tc + j][n];
        *(bf16x4*)(out + (size_t)(n0 + n) * 2048 + k0 + tc) = o;
    }
}

// ---------------- V^T: qkvb V-section (s-major) -> vT[bh][vd][s] ----------------
__global__ __launch_bounds__(256) void k_vt(const bf16* __restrict__ qkv, bf16* __restrict__ vT) {
    int st = blockIdx.x, dt = blockIdx.y, bh = blockIdx.z;
    int b = bh >> 4, h = bh & 15;
    __shared__ bf16 tile[64][72];
    int r = threadIdx.x >> 3, c8 = (threadIdx.x & 7) * 8;
    const bf16* src = qkv + (size_t)(b * Sc + st * 64) * NCAT + 2 * NQ + h * VDc + dt * 64;
#pragma unroll
    for (int i = 0; i < 2; i++) {
        int rr = r + i * 32;   // s_local
        *(bf16x8*)&tile[rr][c8] = *(const bf16x8*)(src + (size_t)rr * NCAT + c8);
    }
    __syncthreads();
    bf16* dst = vT + ((size_t)bh * 128 + dt * 64) * Sc + st * 64;
#pragma unroll
    for (int i = 0; i < 2; i++) {
        int rr = r + i * 32;   // vd_local
        bf16x8 o;
#pragma unroll
        for (int j = 0; j < 8; j++) o[j] = tile[c8 + j][rr];
        *(bf16x8*)(dst + (size_t)rr * Sc + c8) = o;
    }
}

// ---------------- RoPE cos/sin table: [S][32] each ----------------
__global__ void k_ropetab(float* __restrict__ cosT, float* __restrict__ sinT) {
    int idx = blockIdx.x * 256 + threadIdx.x;  // S*32 = 32768
    int pos = idx >> 5, i = idx & 31;
    float theta = expf(-(float)i * (9.210340371976184f / 32.0f)); // 10000^(-i/32)
    float ang = (float)pos * theta;
    cosT[idx] = cosf(ang);
    sinT[idx] = sinf(ang);
}

// ---------------- RoPE apply in-place on bf16 QKV rows ----------------
__global__ __launch_bounds__(256) void k_rope(bf16* __restrict__ qkv, const float* __restrict__ cosT,
                                              const float* __restrict__ sinT, int secbase) {
    int idx = blockIdx.x * 256 + threadIdx.x;  // B*S*H*8 = 262144
    int g = idx & 7, h = (idx >> 3) & 15, row = idx >> 7;
    int s = row & (Sc - 1);
    bf16* p = qkv + (size_t)row * NCAT + secbase + h * QKDc + NOPEc + g * 8;
    bf16x8 v = *(bf16x8*)p;
    const float* cp = cosT + s * 32 + g * 4;
    const float* sp = sinT + s * 32 + g * 4;
#pragma unroll
    for (int q = 0; q < 4; q++) {
        float x0 = (float)v[2*q], x1 = (float)v[2*q+1];
        float c = cp[q], sn = sp[q];
        v[2*q]   = (bf16)(x0 * c - x1 * sn);
        v[2*q+1] = (bf16)(x1 * c + x0 * sn);
    }
    *(bf16x8*)p = v;
}

// ---------------- m97-style 128x128 GEMM: C = A(MxK) * Bt(NxK)^T ----------------
// Grid is 1-D, XCD-swizzled: 16 row-tiles fast within an XCD, col-panels pinned to XCDs.
DEVI void gload16(const bf16* g, bf16* l) {
    __builtin_amdgcn_global_load_lds((const __attribute__((address_space(1))) void*)g,
                                     (__attribute__((address_space(3))) void*)l, 16, 0, 0);
}

template<bool OUT_BF16, bool BIAS>
__global__ __launch_bounds__(256) void k_gemm(const bf16* __restrict__ A, const bf16* __restrict__ Bt,
                                              void* __restrict__ Cptr, const float* __restrict__ bias,
                                              int N, int K) {
    __shared__ __align__(16) bf16 As[128 * 32];
    __shared__ __align__(16) bf16 Bs[128 * 32];
    const int bid = blockIdx.x;
    const int xcd = bid & 7, g = bid >> 3;
    const int rt = g & 15;                 // 16 row-tiles (M=2048 always)
    const int ct = xcd + 8 * (g >> 4);     // col-panel pinned to XCD
    const int tid = threadIdx.x;
    const int l = tid & 63, w = tid >> 6;
    const int lg = l >> 4, lc = l & 15;
    const int wr = (w >> 1) * 64, wc = (w & 1) * 64;
    const int row0 = rt * 128, col0 = ct * 128;
    const int srow = tid >> 2, sseg = (tid & 3) * 8;
    const bf16* Ag = A  + (size_t)(row0 + srow) * K + sseg;
    const bf16* Bg = Bt + (size_t)(col0 + srow) * K + sseg;
    bf16* Asl = As + srow * 32 + sseg;
    bf16* Bsl = Bs + srow * 32 + sseg;
    f32x4 acc[4][4] = {};
    for (int kt = 0; kt < K; kt += 32) {
        __syncthreads();
        gload16(Ag,          Asl);
        gload16(Ag + 64 * K, Asl + 64 * 32);
        gload16(Bg,          Bsl);
        gload16(Bg + 64 * K, Bsl + 64 * 32);
        Ag += 32; Bg += 32;
        __syncthreads();
        bf16x8 aF[4], bF[4];
#pragma unroll
        for (int m = 0; m < 4; m++) aF[m] = *(const bf16x8*)(As + (wr + m * 16 + lc) * 32 + lg * 8);
#pragma unroll
        for (int n = 0; n < 4; n++) bF[n] = *(const bf16x8*)(Bs + (wc + n * 16 + lc) * 32 + lg * 8);
#pragma unroll
        for (int m = 0; m < 4; m++)
#pragma unroll
            for (int n = 0; n < 4; n++)
                acc[m][n] = __builtin_amdgcn_mfma_f32_16x16x32_bf16(aF[m], bF[n], acc[m][n], 0, 0, 0);
    }
#pragma unroll
    for (int m = 0; m < 4; m++)
#pragma unroll
        for (int n = 0; n < 4; n++)
#pragma unroll
            for (int j = 0; j < 4; j++) {
                int r = row0 + wr + m * 16 + lg * 4 + j;
                int c = col0 + wc + n * 16 + lc;
                float v = acc[m][n][j];
                if (BIAS) v += bias[c];
                if (OUT_BF16) ((bf16*)Cptr)[(size_t)r * N + c] = (bf16)v;
                else          ((float*)Cptr)[(size_t)r * N + c] = v;
            }
}

// ---------------- flash attention: barrier-free, K/V^T straight from L2 ----------------
// 1-D grid of 512, mapped so all 16 q-tiles of one (b,h) share an XCD; heavy tiles first.
__global__ __launch_bounds__(256) void k_attn(const bf16* __restrict__ qkv, const bf16* __restrict__ vT,
                                              bf16* __restrict__ cv) {
    const int bid = blockIdx.x;
    const int xcd = bid & 7, g = bid >> 3;
    const int qt = 15 - (g & 15);          // heavy q-tiles dispatched first (LPT)
    const int bh = xcd + 8 * (g >> 4);     // all q-tiles of a bh pinned to one XCD
    const int b = bh >> 4, h = bh & 15;
    const int tid = threadIdx.x, l = tid & 63, w = tid >> 6;
    const int lg = l >> 4, lc = l & 15;
    __shared__ __align__(16) bf16 Pl[4][16][72];    // per-wave P tile (no barriers needed)
    const bf16* Qb = qkv + (size_t)b * Sc * NCAT + h * QKDc;
    const bf16* Kb = Qb + NQ;
    const bf16* Vt = vT + (size_t)bh * 128 * Sc;    // [128][1024]

    bf16x8 qF[6];
    const int qrow = qt * 64 + w * 16 + lc;
#pragma unroll
    for (int kc = 0; kc < 6; kc++) qF[kc] = *(const bf16x8*)(Qb + (size_t)qrow * NCAT + kc * 32 + lg * 8);

    f32x4 acc[8] = {};
    float mrow[4] = {-1e30f, -1e30f, -1e30f, -1e30f};
    float lsum[4] = {0.f, 0.f, 0.f, 0.f};
    const float scale = 0.07216878364870323f;  // 192^-0.5

    for (int c = 0; c <= qt; ++c) {
        const int t0 = c * 64;
        // scores: D[r][t] = sum_d Q[r][d] K[t][d]
        f32x4 sc[4] = {};
#pragma unroll
        for (int nt = 0; nt < 4; nt++)
#pragma unroll
            for (int kc = 0; kc < 6; kc++) {
                bf16x8 kf = *(const bf16x8*)(Kb + (size_t)(t0 + nt * 16 + lc) * NCAT + kc * 32 + lg * 8);
                sc[nt] = __builtin_amdgcn_mfma_f32_16x16x32_bf16(qF[kc], kf, sc[nt], 0, 0, 0);
            }
        // scale + causal mask + online softmax
        float p[4][4];
        float cmax[4] = {-1e30f, -1e30f, -1e30f, -1e30f};
        const bool diag = (c == qt);
#pragma unroll
        for (int nt = 0; nt < 4; nt++)
#pragma unroll
            for (int j = 0; j < 4; j++) {
                float v = sc[nt][j] * scale;
                if (diag) {
                    int tg = t0 + nt * 16 + lc;
                    int rg = qt * 64 + w * 16 + lg * 4 + j;
                    if (tg > rg) v = -1e9f;
                }
                p[nt][j] = v;
                cmax[j] = fmaxf(cmax[j], v);
            }
#pragma unroll
        for (int j = 0; j < 4; j++)
#pragma unroll
            for (int d = 1; d < 16; d <<= 1) cmax[j] = fmaxf(cmax[j], __shfl_xor(cmax[j], d));
        float f[4];
#pragma unroll
        for (int j = 0; j < 4; j++) {
            float nm = fmaxf(mrow[j], cmax[j]);
            f[j] = __expf(mrow[j] - nm);
            mrow[j] = nm;
        }
        float psum[4] = {0.f, 0.f, 0.f, 0.f};
#pragma unroll
        for (int nt = 0; nt < 4; nt++)
#pragma unroll
            for (int j = 0; j < 4; j++) {
                p[nt][j] = __expf(p[nt][j] - mrow[j]);
                psum[j] += p[nt][j];
            }
#pragma unroll
        for (int j = 0; j < 4; j++) {
#pragma unroll
            for (int d = 1; d < 16; d <<= 1) psum[j] += __shfl_xor(psum[j], d);
            lsum[j] = lsum[j] * f[j] + psum[j];
        }
#pragma unroll
        for (int n = 0; n < 8; n++)
#pragma unroll
            for (int j = 0; j < 4; j++) acc[n][j] *= f[j];
        // P -> per-wave LDS (D layout) then re-read as A fragments
#pragma unroll
        for (int nt = 0; nt < 4; nt++)
#pragma unroll
            for (int j = 0; j < 4; j++)
                Pl[w][lg * 4 + j][nt * 16 + lc] = (bf16)p[nt][j];
#pragma unroll
        for (int ks = 0; ks < 2; ks++) {
            bf16x8 aP = *(const bf16x8*)(&Pl[w][lc][ks * 32 + lg * 8]);
#pragma unroll
            for (int n = 0; n < 8; n++) {
                bf16x8 bV = *(const bf16x8*)(Vt + (size_t)(n * 16 + lc) * Sc + t0 + ks * 32 + lg * 8);
                acc[n] = __builtin_amdgcn_mfma_f32_16x16x32_bf16(aP, bV, acc[n], 0, 0, 0);
            }
        }
    }
    // epilogue: O /= lsum, write (B,S,H,VD) bf16
#pragma unroll
    for (int j = 0; j < 4; j++) {
        float inv = 1.0f / lsum[j];
        int r = qt * 64 + w * 16 + lg * 4 + j;
#pragma unroll
        for (int n = 0; n < 8; n++) {
            float v = acc[n][j] * inv;
            cv[((size_t)(b * Sc + r) * Hc + h) * VDc + n * 16 + lc] = (bf16)v;
        }
    }
}

// ---------------- launch ----------------
extern "C" void kernel_launch(void* const* d_in, const int* in_sizes, int n_in,
                              void* d_out, int out_size, void* d_ws, size_t ws_size,
                              hipStream_t stream) {
    const float* x  = (const float*)d_in[0];
    const float* Wq = (const float*)d_in[1];
    const float* Wk = (const float*)d_in[2];
    const float* Wv = (const float*)d_in[3];
    const float* Wo = (const float*)d_in[4];
    const float* bo = (const float*)d_in[5];
    float* out = (float*)d_out;
    char* ws = (char*)d_ws;

    // workspace layout (bytes)
    bf16*  wcat = (bf16*)(ws + 0);           // 8192x2048 bf16 = 33554432
    bf16*  woT  = (bf16*)(ws + 33554432);    // 2048x2048 bf16 =  8388608
    bf16*  xb   = (bf16*)(ws + 41943040);    // 2048x2048 bf16 =  8388608
    bf16*  qkvb = (bf16*)(ws + 50331648);    // 2048x8192 bf16 = 33554432
    bf16*  cvb  = (bf16*)(ws + 83886080);    // 2048x2048 bf16 =  8388608
    bf16*  vTb  = (bf16*)(ws + 92274688);    // 32x128x1024 bf16 = 8388608
    float* cosT = (float*)(ws + 100663296);  // 1024x32 f32    =   131072
    float* sinT = (float*)(ws + 100794368);  // 1024x32 f32    =   131072
    // total: 100925440 bytes (~96.3 MiB)

    k_cvt<<<2048, 256, 0, stream>>>(x, xb);
    k_transpose<<<dim3(32, 48), 256, 0, stream>>>(Wq, wcat, 3072);
    k_transpose<<<dim3(32, 48), 256, 0, stream>>>(Wk, wcat + (size_t)3072 * 2048, 3072);
    k_transpose<<<dim3(32, 32), 256, 0, stream>>>(Wv, wcat + (size_t)6144 * 2048, 2048);
    k_transpose<<<dim3(32, 32), 256, 0, stream>>>(Wo, woT, 2048);
    k_ropetab<<<128, 256, 0, stream>>>(cosT, sinT);
    // fused QKV projection: (2048x2048) x (8192x2048)^T -> (2048x8192) bf16
    k_gemm<true, false><<<1024, 256, 0, stream>>>(xb, wcat, qkvb, nullptr, NCAT, DIMc);
    k_rope<<<1024, 256, 0, stream>>>(qkvb, cosT, sinT, 0);     // Q section
    k_rope<<<1024, 256, 0, stream>>>(qkvb, cosT, sinT, NQ);    // K section
    k_vt<<<dim3(16, 2, 32), 256, 0, stream>>>(qkvb, vTb);      // V^T for PV B-frags
    k_attn<<<512, 256, 0, stream>>>(qkvb, vTb, cvb);
    // output projection with bias: (2048x2048) x (2048x2048)^T -> fp32 out
    k_gemm<false, true><<<256, 256, 0, stream>>>(cvb, woT, out, bo, DIMc, DIMc);
}

// Round 3
// 246.097 us; speedup vs baseline: 1.3435x; 1.3435x over previous
//
#include <hip/hip_runtime.h>

// MLA forward: out = softmax_causal( rope(x@Wq) @ rope(x@Wk)^T / sqrt(192) ) @ (x@Wv) @ Wo + bo
// bf16 MFMA everywhere (threshold is 2% of max|ref|), fp32 accumulation.
// R3: attn = cooperative async K/V LDS staging (global_load_lds w=16, source-side XOR swizzle),
//     software-pipelined with __syncthreads drains, 49KB LDS -> 3 blocks/CU.

typedef __bf16 bf16;
typedef __bf16 bf16x8 __attribute__((ext_vector_type(8)));
typedef __bf16 bf16x4 __attribute__((ext_vector_type(4)));
typedef float  f32x4  __attribute__((ext_vector_type(4)));

#define DEVI __device__ __forceinline__

static constexpr int Bc = 2, Sc = 1024, DIMc = 2048, Hc = 16;
static constexpr int NOPEc = 128, QKDc = 192, VDc = 128;
static constexpr int NQ    = Hc * QKDc;        // 3072
static constexpr int NCAT  = NQ + NQ + Hc*VDc; // 8192  [Q | K | V] per row

// ---------------- fp32 -> bf16 convert (vectorized) ----------------
__global__ __launch_bounds__(256) void k_cvt(const float* __restrict__ in, bf16* __restrict__ out) {
    int i = (blockIdx.x * 256 + threadIdx.x) * 8;
    float4 a = *(const float4*)(in + i);
    float4 b = *(const float4*)(in + i + 4);
    bf16x8 o;
    o[0]=(bf16)a.x; o[1]=(bf16)a.y; o[2]=(bf16)a.z; o[3]=(bf16)a.w;
    o[4]=(bf16)b.x; o[5]=(bf16)b.y; o[6]=(bf16)b.z; o[7]=(bf16)b.w;
    *(bf16x8*)(out + i) = o;
}

// ---------------- transpose + convert: in (K x N) fp32 -> out (N x K=2048) bf16 ----------------
__global__ __launch_bounds__(256) void k_transpose(const float* __restrict__ in, bf16* __restrict__ out, int N) {
    __shared__ float tile[64][68];
    int k0 = blockIdx.x * 64, n0 = blockIdx.y * 64;
    int tr = threadIdx.x >> 4, tc = (threadIdx.x & 15) * 4;
#pragma unroll
    for (int i = 0; i < 4; i++) {
        int r = tr + i * 16;
        float4 v = *(const float4*)(in + (size_t)(k0 + r) * N + n0 + tc);
        tile[r][tc+0] = v.x; tile[r][tc+1] = v.y; tile[r][tc+2] = v.z; tile[r][tc+3] = v.w;
    }
    __syncthreads();
#pragma unroll
    for (int i = 0; i < 4; i++) {
        int n = tr + i * 16;
        bf16x4 o;
#pragma unroll
        for (int j = 0; j < 4; j++) o[j] = (bf16)tile[tc + j][n];
        *(bf16x4*)(out + (size_t)(n0 + n) * 2048 + k0 + tc) = o;
    }
}

// ---------------- V^T: qkvb V-section (s-major) -> vT[bh][vd][s] ----------------
__global__ __launch_bounds__(256) void k_vt(const bf16* __restrict__ qkv, bf16* __restrict__ vT) {
    int st = blockIdx.x, dt = blockIdx.y, bh = blockIdx.z;
    int b = bh >> 4, h = bh & 15;
    __shared__ bf16 tile[64][72];
    int r = threadIdx.x >> 3, c8 = (threadIdx.x & 7) * 8;
    const bf16* src = qkv + (size_t)(b * Sc + st * 64) * NCAT + 2 * NQ + h * VDc + dt * 64;
#pragma unroll
    for (int i = 0; i < 2; i++) {
        int rr = r + i * 32;   // s_local
        *(bf16x8*)&tile[rr][c8] = *(const bf16x8*)(src + (size_t)rr * NCAT + c8);
    }
    __syncthreads();
    bf16* dst = vT + ((size_t)bh * 128 + dt * 64) * Sc + st * 64;
#pragma unroll
    for (int i = 0; i < 2; i++) {
        int rr = r + i * 32;   // vd_local
        bf16x8 o;
#pragma unroll
        for (int j = 0; j < 8; j++) o[j] = tile[c8 + j][rr];
        *(bf16x8*)(dst + (size_t)rr * Sc + c8) = o;
    }
}

// ---------------- RoPE cos/sin table: [S][32] each ----------------
__global__ void k_ropetab(float* __restrict__ cosT, float* __restrict__ sinT) {
    int idx = blockIdx.x * 256 + threadIdx.x;  // S*32 = 32768
    int pos = idx >> 5, i = idx & 31;
    float theta = expf(-(float)i * (9.210340371976184f / 32.0f)); // 10000^(-i/32)
    float ang = (float)pos * theta;
    cosT[idx] = cosf(ang);
    sinT[idx] = sinf(ang);
}

// ---------------- RoPE apply in-place on bf16 QKV rows ----------------
__global__ __launch_bounds__(256) void k_rope(bf16* __restrict__ qkv, const float* __restrict__ cosT,
                                              const float* __restrict__ sinT, int secbase) {
    int idx = blockIdx.x * 256 + threadIdx.x;  // B*S*H*8 = 262144
    int g = idx & 7, h = (idx >> 3) & 15, row = idx >> 7;
    int s = row & (Sc - 1);
    bf16* p = qkv + (size_t)row * NCAT + secbase + h * QKDc + NOPEc + g * 8;
    bf16x8 v = *(bf16x8*)p;
    const float* cp = cosT + s * 32 + g * 4;
    const float* sp = sinT + s * 32 + g * 4;
#pragma unroll
    for (int q = 0; q < 4; q++) {
        float x0 = (float)v[2*q], x1 = (float)v[2*q+1];
        float c = cp[q], sn = sp[q];
        v[2*q]   = (bf16)(x0 * c - x1 * sn);
        v[2*q+1] = (bf16)(x1 * c + x0 * sn);
    }
    *(bf16x8*)p = v;
}

// ---------------- async global->LDS, 16B per lane ----------------
DEVI void gload16(const bf16* g, bf16* l) {
    __builtin_amdgcn_global_load_lds((const __attribute__((address_space(1))) void*)g,
                                     (__attribute__((address_space(3))) void*)l, 16, 0, 0);
}

// ---------------- m97-style 128x128 GEMM: C = A(MxK) * Bt(NxK)^T ----------------
template<bool OUT_BF16, bool BIAS>
__global__ __launch_bounds__(256) void k_gemm(const bf16* __restrict__ A, const bf16* __restrict__ Bt,
                                              void* __restrict__ Cptr, const float* __restrict__ bias,
                                              int N, int K) {
    __shared__ __align__(16) bf16 As[128 * 32];
    __shared__ __align__(16) bf16 Bs[128 * 32];
    const int bid = blockIdx.x;
    const int xcd = bid & 7, g = bid >> 3;
    const int rt = g & 15;                 // 16 row-tiles (M=2048 always)
    const int ct = xcd + 8 * (g >> 4);     // col-panel pinned to XCD
    const int tid = threadIdx.x;
    const int l = tid & 63, w = tid >> 6;
    const int lg = l >> 4, lc = l & 15;
    const int wr = (w >> 1) * 64, wc = (w & 1) * 64;
    const int row0 = rt * 128, col0 = ct * 128;
    const int srow = tid >> 2, sseg = (tid & 3) * 8;
    const bf16* Ag = A  + (size_t)(row0 + srow) * K + sseg;
    const bf16* Bg = Bt + (size_t)(col0 + srow) * K + sseg;
    bf16* Asl = As + srow * 32 + sseg;
    bf16* Bsl = Bs + srow * 32 + sseg;
    f32x4 acc[4][4] = {};
    for (int kt = 0; kt < K; kt += 32) {
        __syncthreads();
        gload16(Ag,          Asl);
        gload16(Ag + 64 * K, Asl + 64 * 32);
        gload16(Bg,          Bsl);
        gload16(Bg + 64 * K, Bsl + 64 * 32);
        Ag += 32; Bg += 32;
        __syncthreads();
        bf16x8 aF[4], bF[4];
#pragma unroll
        for (int m = 0; m < 4; m++) aF[m] = *(const bf16x8*)(As + (wr + m * 16 + lc) * 32 + lg * 8);
#pragma unroll
        for (int n = 0; n < 4; n++) bF[n] = *(const bf16x8*)(Bs + (wc + n * 16 + lc) * 32 + lg * 8);
#pragma unroll
        for (int m = 0; m < 4; m++)
#pragma unroll
            for (int n = 0; n < 4; n++)
                acc[m][n] = __builtin_amdgcn_mfma_f32_16x16x32_bf16(aF[m], bF[n], acc[m][n], 0, 0, 0);
    }
#pragma unroll
    for (int m = 0; m < 4; m++)
#pragma unroll
        for (int n = 0; n < 4; n++)
#pragma unroll
            for (int j = 0; j < 4; j++) {
                int r = row0 + wr + m * 16 + lg * 4 + j;
                int c = col0 + wc + n * 16 + lc;
                float v = acc[m][n][j];
                if (BIAS) v += bias[c];
                if (OUT_BF16) ((bf16*)Cptr)[(size_t)r * N + c] = (bf16)v;
                else          ((float*)Cptr)[(size_t)r * N + c] = v;
            }
}

// ---------------- flash attention: K/V cooperatively LDS-staged, pipelined ----------------
// Grid 512, XCD-pinned per bh, heavy q-tiles first. 4 waves x 16 q-rows.
// LDS 50176B -> 3 blocks/CU. K row=384B, V row=128B: both 0 mod 32 banks, so
// 16B units are XOR-swizzled on the GLOBAL side (gload_lds writes linearly) and
// the same XOR applied on ds_read -> free 2-way conflicts.
__global__ __launch_bounds__(256, 3) void k_attn(const bf16* __restrict__ qkv, const bf16* __restrict__ vT,
                                                 bf16* __restrict__ cv) {
    const int bid = blockIdx.x;
    const int xcd = bid & 7, g = bid >> 3;
    const int qt = 15 - (g & 15);          // heavy q-tiles dispatched first (LPT)
    const int bh = xcd + 8 * (g >> 4);     // all q-tiles of a bh pinned to one XCD
    const int b = bh >> 4, h = bh & 15;
    const int tid = threadIdx.x, l = tid & 63, w = tid >> 6;
    const int lg = l >> 4, lc = l & 15;
    __shared__ __align__(16) bf16 Ks[64 * 192];     // 24576 B  [row][24 x 16B-unit], unit swizzled
    __shared__ __align__(16) bf16 Vs[128 * 64];     // 16384 B  [vd][8 x 16B-unit], unit swizzled
    __shared__ __align__(16) bf16 Pl[4][16][72];    //  9216 B  per-wave P tile
    const bf16* Qb = qkv + (size_t)b * Sc * NCAT + h * QKDc;
    const bf16* Kb = Qb + NQ;
    const bf16* Vt = vT + (size_t)bh * 128 * Sc;    // [128][1024]

    // staging source offsets (element units), swizzle folded in:
    // LDS unit li=(row,c) holds global unit (row, c ^ (row&7))
    int sK[6];
#pragma unroll
    for (int r = 0; r < 6; r++) {
        int li = r * 256 + tid;
        int row = li / 24, c16 = li - row * 24;
        sK[r] = row * NCAT + ((c16 ^ (row & 7)) * 8);
    }
    int sV[4];
#pragma unroll
    for (int r = 0; r < 4; r++) {
        int li = r * 256 + tid;
        int row = li >> 3, c16 = li & 7;
        sV[r] = row * Sc + ((c16 ^ (row & 7)) * 8);
    }
    const int swz = lc & 7;   // read-side XOR (row&7 == lc&7 for 16-aligned row tiles)

    bf16x8 qF[6];
    const int qrow = qt * 64 + w * 16 + lc;
#pragma unroll
    for (int kc = 0; kc < 6; kc++) qF[kc] = *(const bf16x8*)(Qb + (size_t)qrow * NCAT + kc * 32 + lg * 8);

    f32x4 acc[8] = {};
    float mrow[4] = {-1e30f, -1e30f, -1e30f, -1e30f};
    float lsum[4] = {0.f, 0.f, 0.f, 0.f};
    const float scale = 0.07216878364870323f;  // 192^-0.5

    // prologue: stage K[0]
#pragma unroll
    for (int r = 0; r < 6; r++) gload16(Kb + sK[r], Ks + (r * 256 + tid) * 8);

    for (int c = 0; c <= qt; ++c) {
        const int t0 = c * 64;
        __syncthreads();   // B1: drains vmcnt -> K[c] staged; all waves done with V[c-1]
        // stage V[c] (drained by B2, read in PV below)
#pragma unroll
        for (int r = 0; r < 4; r++) gload16(Vt + t0 + sV[r], Vs + (r * 256 + tid) * 8);
        // QK^T from LDS: D[r][t] = sum_d Q[r][d] K[t][d]
        f32x4 sc[4] = {};
#pragma unroll
        for (int nt = 0; nt < 4; nt++)
#pragma unroll
            for (int kc = 0; kc < 6; kc++) {
                bf16x8 kf = *(const bf16x8*)(Ks + (nt * 16 + lc) * 192 + (((kc * 4 + lg) ^ swz) * 8));
                sc[nt] = __builtin_amdgcn_mfma_f32_16x16x32_bf16(qF[kc], kf, sc[nt], 0, 0, 0);
            }
        __syncthreads();   // B2: all waves done reading K[c]; drains vmcnt -> V[c] staged
        // stage K[c+1]: latency hidden under softmax + PV + B1
        if (c < qt) {
#pragma unroll
            for (int r = 0; r < 6; r++) gload16(Kb + (size_t)(t0 + 64) * NCAT + sK[r], Ks + (r * 256 + tid) * 8);
        }
        // scale + causal mask + online softmax
        float p[4][4];
        float cmax[4] = {-1e30f, -1e30f, -1e30f, -1e30f};
        const bool diag = (c == qt);
#pragma unroll
        for (int nt = 0; nt < 4; nt++)
#pragma unroll
            for (int j = 0; j < 4; j++) {
                float v = sc[nt][j] * scale;
                if (diag) {
                    int tg = t0 + nt * 16 + lc;
                    int rg = qt * 64 + w * 16 + lg * 4 + j;
                    if (tg > rg) v = -1e9f;
                }
                p[nt][j] = v;
                cmax[j] = fmaxf(cmax[j], v);
            }
#pragma unroll
        for (int j = 0; j < 4; j++)
#pragma unroll
            for (int d = 1; d < 16; d <<= 1) cmax[j] = fmaxf(cmax[j], __shfl_xor(cmax[j], d));
        float f[4];
#pragma unroll
        for (int j = 0; j < 4; j++) {
            float nm = fmaxf(mrow[j], cmax[j]);
            f[j] = __expf(mrow[j] - nm);
            mrow[j] = nm;
        }
        float psum[4] = {0.f, 0.f, 0.f, 0.f};
#pragma unroll
        for (int nt = 0; nt < 4; nt++)
#pragma unroll
            for (int j = 0; j < 4; j++) {
                p[nt][j] = __expf(p[nt][j] - mrow[j]);
                psum[j] += p[nt][j];
            }
#pragma unroll
        for (int j = 0; j < 4; j++) {
#pragma unroll
            for (int d = 1; d < 16; d <<= 1) psum[j] += __shfl_xor(psum[j], d);
            lsum[j] = lsum[j] * f[j] + psum[j];
        }
#pragma unroll
        for (int n = 0; n < 8; n++)
#pragma unroll
            for (int j = 0; j < 4; j++) acc[n][j] *= f[j];
        // P -> per-wave LDS (D layout) then re-read as A fragments
#pragma unroll
        for (int nt = 0; nt < 4; nt++)
#pragma unroll
            for (int j = 0; j < 4; j++)
                Pl[w][lg * 4 + j][nt * 16 + lc] = (bf16)p[nt][j];
#pragma unroll
        for (int ks = 0; ks < 2; ks++) {
            bf16x8 aP = *(const bf16x8*)(&Pl[w][lc][ks * 32 + lg * 8]);
#pragma unroll
            for (int n = 0; n < 8; n++) {
                bf16x8 bV = *(const bf16x8*)(Vs + (n * 16 + lc) * 64 + (((ks * 4 + lg) ^ swz) * 8));
                acc[n] = __builtin_amdgcn_mfma_f32_16x16x32_bf16(aP, bV, acc[n], 0, 0, 0);
            }
        }
    }
    // epilogue: O /= lsum, write (B,S,H,VD) bf16
#pragma unroll
    for (int j = 0; j < 4; j++) {
        float inv = 1.0f / lsum[j];
        int r = qt * 64 + w * 16 + lg * 4 + j;
#pragma unroll
        for (int n = 0; n < 8; n++) {
            float v = acc[n][j] * inv;
            cv[((size_t)(b * Sc + r) * Hc + h) * VDc + n * 16 + lc] = (bf16)v;
        }
    }
}

// ---------------- launch ----------------
extern "C" void kernel_launch(void* const* d_in, const int* in_sizes, int n_in,
                              void* d_out, int out_size, void* d_ws, size_t ws_size,
                              hipStream_t stream) {
    const float* x  = (const float*)d_in[0];
    const float* Wq = (const float*)d_in[1];
    const float* Wk = (const float*)d_in[2];
    const float* Wv = (const float*)d_in[3];
    const float* Wo = (const float*)d_in[4];
    const float* bo = (const float*)d_in[5];
    float* out = (float*)d_out;
    char* ws = (char*)d_ws;

    // workspace layout (bytes)
    bf16*  wcat = (bf16*)(ws + 0);           // 8192x2048 bf16 = 33554432
    bf16*  woT  = (bf16*)(ws + 33554432);    // 2048x2048 bf16 =  8388608
    bf16*  xb   = (bf16*)(ws + 41943040);    // 2048x2048 bf16 =  8388608
    bf16*  qkvb = (bf16*)(ws + 50331648);    // 2048x8192 bf16 = 33554432
    bf16*  cvb  = (bf16*)(ws + 83886080);    // 2048x2048 bf16 =  8388608
    bf16*  vTb  = (bf16*)(ws + 92274688);    // 32x128x1024 bf16 = 8388608
    float* cosT = (float*)(ws + 100663296);  // 1024x32 f32    =   131072
    float* sinT = (float*)(ws + 100794368);  // 1024x32 f32    =   131072
    // total: 100925440 bytes (~96.3 MiB)

    k_cvt<<<2048, 256, 0, stream>>>(x, xb);
    k_transpose<<<dim3(32, 48), 256, 0, stream>>>(Wq, wcat, 3072);
    k_transpose<<<dim3(32, 48), 256, 0, stream>>>(Wk, wcat + (size_t)3072 * 2048, 3072);
    k_transpose<<<dim3(32, 32), 256, 0, stream>>>(Wv, wcat + (size_t)6144 * 2048, 2048);
    k_transpose<<<dim3(32, 32), 256, 0, stream>>>(Wo, woT, 2048);
    k_ropetab<<<128, 256, 0, stream>>>(cosT, sinT);
    // fused QKV projection: (2048x2048) x (8192x2048)^T -> (2048x8192) bf16
    k_gemm<true, false><<<1024, 256, 0, stream>>>(xb, wcat, qkvb, nullptr, NCAT, DIMc);
    k_rope<<<1024, 256, 0, stream>>>(qkvb, cosT, sinT, 0);     // Q section
    k_rope<<<1024, 256, 0, stream>>>(qkvb, cosT, sinT, NQ);    // K section
    k_vt<<<dim3(16, 2, 32), 256, 0, stream>>>(qkvb, vTb);      // V^T for PV B-frags
    k_attn<<<512, 256, 0, stream>>>(qkvb, vTb, cvb);
    // output projection with bias: (2048x2048) x (2048x2048)^T -> fp32 out
    k_gemm<false, true><<<256, 256, 0, stream>>>(cvb, woT, out, bo, DIMc, DIMc);
}

// Round 4
// 208.013 us; speedup vs baseline: 1.5894x; 1.1831x over previous
//
#include <hip/hip_runtime.h>

// MLA forward: out = softmax_causal( rope(x@Wq) @ rope(x@Wk)^T / sqrt(192) ) @ (x@Wv) @ Wo + bo
// bf16 MFMA everywhere (threshold is 2% of max|ref|), fp32 accumulation.
// R4: QKV GEMM -> 256x256 multi-phase template (T2 swizzle + T3/T4 counted vmcnt + T5 setprio),
//     8 waves, 128KB dbuf LDS, raw s_barrier (no vmcnt(0) drain in main loop).

typedef __bf16 bf16;
typedef __bf16 bf16x8 __attribute__((ext_vector_type(8)));
typedef __bf16 bf16x4 __attribute__((ext_vector_type(4)));
typedef float  f32x4  __attribute__((ext_vector_type(4)));

#define DEVI __device__ __forceinline__

static constexpr int Bc = 2, Sc = 1024, DIMc = 2048, Hc = 16;
static constexpr int NOPEc = 128, QKDc = 192, VDc = 128;
static constexpr int NQ    = Hc * QKDc;        // 3072
static constexpr int NCAT  = NQ + NQ + Hc*VDc; // 8192  [Q | K | V] per row

// ---------------- fp32 -> bf16 convert (vectorized) ----------------
__global__ __launch_bounds__(256) void k_cvt(const float* __restrict__ in, bf16* __restrict__ out) {
    int i = (blockIdx.x * 256 + threadIdx.x) * 8;
    float4 a = *(const float4*)(in + i);
    float4 b = *(const float4*)(in + i + 4);
    bf16x8 o;
    o[0]=(bf16)a.x; o[1]=(bf16)a.y; o[2]=(bf16)a.z; o[3]=(bf16)a.w;
    o[4]=(bf16)b.x; o[5]=(bf16)b.y; o[6]=(bf16)b.z; o[7]=(bf16)b.w;
    *(bf16x8*)(out + i) = o;
}

// ---------------- transpose + convert: in (K x N) fp32 -> out (N x K=2048) bf16 ----------------
__global__ __launch_bounds__(256) void k_transpose(const float* __restrict__ in, bf16* __restrict__ out, int N) {
    __shared__ float tile[64][68];
    int k0 = blockIdx.x * 64, n0 = blockIdx.y * 64;
    int tr = threadIdx.x >> 4, tc = (threadIdx.x & 15) * 4;
#pragma unroll
    for (int i = 0; i < 4; i++) {
        int r = tr + i * 16;
        float4 v = *(const float4*)(in + (size_t)(k0 + r) * N + n0 + tc);
        tile[r][tc+0] = v.x; tile[r][tc+1] = v.y; tile[r][tc+2] = v.z; tile[r][tc+3] = v.w;
    }
    __syncthreads();
#pragma unroll
    for (int i = 0; i < 4; i++) {
        int n = tr + i * 16;
        bf16x4 o;
#pragma unroll
        for (int j = 0; j < 4; j++) o[j] = (bf16)tile[tc + j][n];
        *(bf16x4*)(out + (size_t)(n0 + n) * 2048 + k0 + tc) = o;
    }
}

// ---------------- V^T: qkvb V-section (s-major) -> vT[bh][vd][s] ----------------
__global__ __launch_bounds__(256) void k_vt(const bf16* __restrict__ qkv, bf16* __restrict__ vT) {
    int st = blockIdx.x, dt = blockIdx.y, bh = blockIdx.z;
    int b = bh >> 4, h = bh & 15;
    __shared__ bf16 tile[64][72];
    int r = threadIdx.x >> 3, c8 = (threadIdx.x & 7) * 8;
    const bf16* src = qkv + (size_t)(b * Sc + st * 64) * NCAT + 2 * NQ + h * VDc + dt * 64;
#pragma unroll
    for (int i = 0; i < 2; i++) {
        int rr = r + i * 32;   // s_local
        *(bf16x8*)&tile[rr][c8] = *(const bf16x8*)(src + (size_t)rr * NCAT + c8);
    }
    __syncthreads();
    bf16* dst = vT + ((size_t)bh * 128 + dt * 64) * Sc + st * 64;
#pragma unroll
    for (int i = 0; i < 2; i++) {
        int rr = r + i * 32;   // vd_local
        bf16x8 o;
#pragma unroll
        for (int j = 0; j < 8; j++) o[j] = tile[c8 + j][rr];
        *(bf16x8*)(dst + (size_t)rr * Sc + c8) = o;
    }
}

// ---------------- RoPE cos/sin table: [S][32] each ----------------
__global__ void k_ropetab(float* __restrict__ cosT, float* __restrict__ sinT) {
    int idx = blockIdx.x * 256 + threadIdx.x;  // S*32 = 32768
    int pos = idx >> 5, i = idx & 31;
    float theta = expf(-(float)i * (9.210340371976184f / 32.0f)); // 10000^(-i/32)
    float ang = (float)pos * theta;
    cosT[idx] = cosf(ang);
    sinT[idx] = sinf(ang);
}

// ---------------- RoPE apply in-place on bf16 QKV rows ----------------
__global__ __launch_bounds__(256) void k_rope(bf16* __restrict__ qkv, const float* __restrict__ cosT,
                                              const float* __restrict__ sinT, int secbase) {
    int idx = blockIdx.x * 256 + threadIdx.x;  // B*S*H*8 = 262144
    int g = idx & 7, h = (idx >> 3) & 15, row = idx >> 7;
    int s = row & (Sc - 1);
    bf16* p = qkv + (size_t)row * NCAT + secbase + h * QKDc + NOPEc + g * 8;
    bf16x8 v = *(bf16x8*)p;
    const float* cp = cosT + s * 32 + g * 4;
    const float* sp = sinT + s * 32 + g * 4;
#pragma unroll
    for (int q = 0; q < 4; q++) {
        float x0 = (float)v[2*q], x1 = (float)v[2*q+1];
        float c = cp[q], sn = sp[q];
        v[2*q]   = (bf16)(x0 * c - x1 * sn);
        v[2*q+1] = (bf16)(x1 * c + x0 * sn);
    }
    *(bf16x8*)p = v;
}

// ---------------- async global->LDS, 16B per lane ----------------
DEVI void gload16(const bf16* g, bf16* l) {
    __builtin_amdgcn_global_load_lds((const __attribute__((address_space(1))) void*)g,
                                     (__attribute__((address_space(3))) void*)l, 16, 0, 0);
}

// ================= 256x256 multi-phase GEMM (QKV projection) =================
// C = A(MxK) * Bt(NxK)^T, bf16 out. Grid: (M/256)*(N/256) blocks of 512 threads.
// K-tile BK=64 staged as 4 K-slices [256][32] (A-ks0, B-ks0, A-ks1, B-ks1), double-buffered.
// 4 phases per K-tile: phase = (ks, mh): 12/8 ds_read_b128 + stage-1-slice + barrier +
// setprio(1) 16 MFMA setprio(0) + counted vmcnt(4) at phases 1,3 + barrier.
// LDS swizzle: 16B-unit u' = u ^ ((row>>1)&3), folded into the GLOBAL source address
// (gload_lds writes linearly); same XOR on ds_read -> every fragment read covers all
// 32 banks exactly 2x (free).
__global__ __launch_bounds__(512, 2) void k_gemm8(const bf16* __restrict__ A, const bf16* __restrict__ Bt,
                                                  bf16* __restrict__ C, int N, int K, int NCT) {
    __shared__ __align__(16) bf16 lds[2][2][2][256 * 32];  // [buf][A=0/B=1][ks][slice] = 128 KiB
    const int tid = threadIdx.x;
    const int l = tid & 63, wid = tid >> 6;
    const int lg = l >> 4, lc = l & 15;
    const int wm = wid >> 2, wn = wid & 3;          // 2x4 wave grid; wave owns 128x64
    const int bid = blockIdx.x;
    const int xcd = bid & 7, g = bid >> 3;
    const int per = NCT >> 3;                        // col-panels per XCD
    const int rt = g & 7, ct = xcd * per + (g >> 3); // 8 row-tiles, panels pinned to XCD
    const int row0 = rt * 256, col0 = ct * 256;
    const int NT = K >> 6;

    const bf16* Abase = A  + (size_t)row0 * K;
    const bf16* Bbase = Bt + (size_t)col0 * K;

    // per-thread staging addressing: LDS li = cc*512+tid -> (row=li>>2, u=li&3);
    // source element = row*K + (u ^ ((row>>1)&3))*8  (swizzle pre-applied to source)
    size_t srcoff0, srcoff1;
    int ldsoff0, ldsoff1;
    {
        int li0 = tid,        r0 = li0 >> 2, u0 = li0 & 3;
        int li1 = 512 + tid,  r1 = li1 >> 2, u1 = li1 & 3;
        srcoff0 = (size_t)r0 * K + ((u0 ^ ((r0 >> 1) & 3)) << 3);  ldsoff0 = li0 * 8;
        srcoff1 = (size_t)r1 * K + ((u1 ^ ((r1 >> 1) & 3)) << 3);  ldsoff1 = li1 * 8;
    }

#define STAGE8(ab, ks, ktile, buf) { \
    const bf16* gb_ = ((ab) ? Bbase : Abase) + (ktile) * 64 + (ks) * 32; \
    bf16* lb_ = &lds[buf][ab][ks][0]; \
    gload16(gb_ + srcoff0, lb_ + ldsoff0); \
    gload16(gb_ + srcoff1, lb_ + ldsoff1); }

    f32x4 acc[8][4] = {};

    // prologue: tile 0 -> buf 0 in order A-ks0, B-ks0, A-ks1, B-ks1 (8 per-thread loads)
    STAGE8(0, 0, 0, 0); STAGE8(1, 0, 0, 0); STAGE8(0, 1, 0, 0); STAGE8(1, 1, 0, 0);
    asm volatile("s_waitcnt vmcnt(4)" ::: "memory");   // ks0 slices landed; ks1 in flight
    __builtin_amdgcn_s_barrier();
    asm volatile("" ::: "memory");

    for (int kt = 0; kt < NT; ++kt) {
        const int cur = kt & 1, nxt = cur ^ 1;
        const bool notlast = (kt + 1 < NT);
        bf16x8 aF[4], bB[4];
#pragma unroll
        for (int ph = 0; ph < 4; ph++) {
            const int ks = ph >> 1, mh = ph & 1;
            const bf16* As_ = &lds[cur][0][ks][0];
            const bf16* Bs_ = &lds[cur][1][ks][0];
            if (mh == 0) {   // B-frags for this ks (reused by mh=1 phase)
#pragma unroll
                for (int fc = 0; fc < 4; fc++) {
                    int row = wn * 64 + fc * 16 + lc;
                    bB[fc] = *(const bf16x8*)(Bs_ + row * 32 + ((lg ^ ((row >> 1) & 3)) << 3));
                }
            }
#pragma unroll
            for (int i = 0; i < 4; i++) {
                int row = wm * 128 + (mh * 4 + i) * 16 + lc;
                aF[i] = *(const bf16x8*)(As_ + row * 32 + ((lg ^ ((row >> 1) & 3)) << 3));
            }
            if (notlast) {   // stage one K-slice of tile kt+1 per phase
                if      (ph == 0) STAGE8(0, 0, kt + 1, nxt)
                else if (ph == 1) STAGE8(1, 0, kt + 1, nxt)
                else if (ph == 2) STAGE8(0, 1, kt + 1, nxt)
                else              STAGE8(1, 1, kt + 1, nxt)
            }
            __builtin_amdgcn_s_barrier();
            asm volatile("" ::: "memory");
            __builtin_amdgcn_s_setprio(1);
#pragma unroll
            for (int i = 0; i < 4; i++)
#pragma unroll
                for (int fc = 0; fc < 4; fc++)
                    acc[mh * 4 + i][fc] =
                        __builtin_amdgcn_mfma_f32_16x16x32_bf16(aF[i], bB[fc], acc[mh * 4 + i][fc], 0, 0, 0);
            __builtin_amdgcn_s_setprio(0);
            if (ph == 1) {   // collective guarantee: ks1(cur tile) landed before phases 2,3 read it
                if (notlast) asm volatile("s_waitcnt vmcnt(4)" ::: "memory");
                else         asm volatile("s_waitcnt vmcnt(0)" ::: "memory");
            }
            if (ph == 3 && notlast) {   // ks0(kt+1) landed before next tile's phases 0,1
                asm volatile("s_waitcnt vmcnt(4)" ::: "memory");
            }
            __builtin_amdgcn_s_barrier();
            asm volatile("" ::: "memory");
        }
    }
#undef STAGE8
    // epilogue: D row = (lane>>4)*4 + reg, col = lane&15  [m89/m91]
#pragma unroll
    for (int m = 0; m < 8; m++)
#pragma unroll
        for (int fc = 0; fc < 4; fc++)
#pragma unroll
            for (int j = 0; j < 4; j++) {
                int r = row0 + wm * 128 + m * 16 + lg * 4 + j;
                int c = col0 + wn * 64 + fc * 16 + lc;
                C[(size_t)r * N + c] = (bf16)acc[m][fc][j];
            }
}

// ---------------- m97-style 128x128 GEMM (kept for the N=2048 out-projection) ----------------
template<bool OUT_BF16, bool BIAS>
__global__ __launch_bounds__(256) void k_gemm(const bf16* __restrict__ A, const bf16* __restrict__ Bt,
                                              void* __restrict__ Cptr, const float* __restrict__ bias,
                                              int N, int K) {
    __shared__ __align__(16) bf16 As[128 * 32];
    __shared__ __align__(16) bf16 Bs[128 * 32];
    const int bid = blockIdx.x;
    const int xcd = bid & 7, g = bid >> 3;
    const int rt = g & 15;
    const int ct = xcd + 8 * (g >> 4);
    const int tid = threadIdx.x;
    const int l = tid & 63, w = tid >> 6;
    const int lg = l >> 4, lc = l & 15;
    const int wr = (w >> 1) * 64, wc = (w & 1) * 64;
    const int row0 = rt * 128, col0 = ct * 128;
    const int srow = tid >> 2, sseg = (tid & 3) * 8;
    const bf16* Ag = A  + (size_t)(row0 + srow) * K + sseg;
    const bf16* Bg = Bt + (size_t)(col0 + srow) * K + sseg;
    bf16* Asl = As + srow * 32 + sseg;
    bf16* Bsl = Bs + srow * 32 + sseg;
    f32x4 acc[4][4] = {};
    for (int kt = 0; kt < K; kt += 32) {
        __syncthreads();
        gload16(Ag,          Asl);
        gload16(Ag + 64 * K, Asl + 64 * 32);
        gload16(Bg,          Bsl);
        gload16(Bg + 64 * K, Bsl + 64 * 32);
        Ag += 32; Bg += 32;
        __syncthreads();
        bf16x8 aF[4], bF[4];
#pragma unroll
        for (int m = 0; m < 4; m++) aF[m] = *(const bf16x8*)(As + (wr + m * 16 + lc) * 32 + lg * 8);
#pragma unroll
        for (int n = 0; n < 4; n++) bF[n] = *(const bf16x8*)(Bs + (wc + n * 16 + lc) * 32 + lg * 8);
#pragma unroll
        for (int m = 0; m < 4; m++)
#pragma unroll
            for (int n = 0; n < 4; n++)
                acc[m][n] = __builtin_amdgcn_mfma_f32_16x16x32_bf16(aF[m], bF[n], acc[m][n], 0, 0, 0);
    }
#pragma unroll
    for (int m = 0; m < 4; m++)
#pragma unroll
        for (int n = 0; n < 4; n++)
#pragma unroll
            for (int j = 0; j < 4; j++) {
                int r = row0 + wr + m * 16 + lg * 4 + j;
                int c = col0 + wc + n * 16 + lc;
                float v = acc[m][n][j];
                if (BIAS) v += bias[c];
                if (OUT_BF16) ((bf16*)Cptr)[(size_t)r * N + c] = (bf16)v;
                else          ((float*)Cptr)[(size_t)r * N + c] = v;
            }
}

// ---------------- flash attention: K/V cooperatively LDS-staged, pipelined ----------------
__global__ __launch_bounds__(256, 3) void k_attn(const bf16* __restrict__ qkv, const bf16* __restrict__ vT,
                                                 bf16* __restrict__ cv) {
    const int bid = blockIdx.x;
    const int xcd = bid & 7, g = bid >> 3;
    const int qt = 15 - (g & 15);          // heavy q-tiles dispatched first (LPT)
    const int bh = xcd + 8 * (g >> 4);     // all q-tiles of a bh pinned to one XCD
    const int b = bh >> 4, h = bh & 15;
    const int tid = threadIdx.x, l = tid & 63, w = tid >> 6;
    const int lg = l >> 4, lc = l & 15;
    __shared__ __align__(16) bf16 Ks[64 * 192];     // 24576 B
    __shared__ __align__(16) bf16 Vs[128 * 64];     // 16384 B
    __shared__ __align__(16) bf16 Pl[4][16][72];    //  9216 B
    const bf16* Qb = qkv + (size_t)b * Sc * NCAT + h * QKDc;
    const bf16* Kb = Qb + NQ;
    const bf16* Vt = vT + (size_t)bh * 128 * Sc;    // [128][1024]

    int sK[6];
#pragma unroll
    for (int r = 0; r < 6; r++) {
        int li = r * 256 + tid;
        int row = li / 24, c16 = li - row * 24;
        sK[r] = row * NCAT + ((c16 ^ (row & 7)) * 8);
    }
    int sV[4];
#pragma unroll
    for (int r = 0; r < 4; r++) {
        int li = r * 256 + tid;
        int row = li >> 3, c16 = li & 7;
        sV[r] = row * Sc + ((c16 ^ (row & 7)) * 8);
    }
    const int swz = lc & 7;

    bf16x8 qF[6];
    const int qrow = qt * 64 + w * 16 + lc;
#pragma unroll
    for (int kc = 0; kc < 6; kc++) qF[kc] = *(const bf16x8*)(Qb + (size_t)qrow * NCAT + kc * 32 + lg * 8);

    f32x4 acc[8] = {};
    float mrow[4] = {-1e30f, -1e30f, -1e30f, -1e30f};
    float lsum[4] = {0.f, 0.f, 0.f, 0.f};
    const float scale = 0.07216878364870323f;  // 192^-0.5

#pragma unroll
    for (int r = 0; r < 6; r++) gload16(Kb + sK[r], Ks + (r * 256 + tid) * 8);

    for (int c = 0; c <= qt; ++c) {
        const int t0 = c * 64;
        __syncthreads();   // B1: drains vmcnt -> K[c] staged
#pragma unroll
        for (int r = 0; r < 4; r++) gload16(Vt + t0 + sV[r], Vs + (r * 256 + tid) * 8);
        f32x4 sc[4] = {};
#pragma unroll
        for (int nt = 0; nt < 4; nt++)
#pragma unroll
            for (int kc = 0; kc < 6; kc++) {
                bf16x8 kf = *(const bf16x8*)(Ks + (nt * 16 + lc) * 192 + (((kc * 4 + lg) ^ swz) * 8));
                sc[nt] = __builtin_amdgcn_mfma_f32_16x16x32_bf16(qF[kc], kf, sc[nt], 0, 0, 0);
            }
        __syncthreads();   // B2: K[c] reads done; drains vmcnt -> V[c] staged
        if (c < qt) {
#pragma unroll
            for (int r = 0; r < 6; r++) gload16(Kb + (size_t)(t0 + 64) * NCAT + sK[r], Ks + (r * 256 + tid) * 8);
        }
        float p[4][4];
        float cmax[4] = {-1e30f, -1e30f, -1e30f, -1e30f};
        const bool diag = (c == qt);
#pragma unroll
        for (int nt = 0; nt < 4; nt++)
#pragma unroll
            for (int j = 0; j < 4; j++) {
                float v = sc[nt][j] * scale;
                if (diag) {
                    int tg = t0 + nt * 16 + lc;
                    int rg = qt * 64 + w * 16 + lg * 4 + j;
                    if (tg > rg) v = -1e9f;
                }
                p[nt][j] = v;
                cmax[j] = fmaxf(cmax[j], v);
            }
#pragma unroll
        for (int j = 0; j < 4; j++)
#pragma unroll
            for (int d = 1; d < 16; d <<= 1) cmax[j] = fmaxf(cmax[j], __shfl_xor(cmax[j], d));
        float f[4];
#pragma unroll
        for (int j = 0; j < 4; j++) {
            float nm = fmaxf(mrow[j], cmax[j]);
            f[j] = __expf(mrow[j] - nm);
            mrow[j] = nm;
        }
        float psum[4] = {0.f, 0.f, 0.f, 0.f};
#pragma unroll
        for (int nt = 0; nt < 4; nt++)
#pragma unroll
            for (int j = 0; j < 4; j++) {
                p[nt][j] = __expf(p[nt][j] - mrow[j]);
                psum[j] += p[nt][j];
            }
#pragma unroll
        for (int j = 0; j < 4; j++) {
#pragma unroll
            for (int d = 1; d < 16; d <<= 1) psum[j] += __shfl_xor(psum[j], d);
            lsum[j] = lsum[j] * f[j] + psum[j];
        }
#pragma unroll
        for (int n = 0; n < 8; n++)
#pragma unroll
            for (int j = 0; j < 4; j++) acc[n][j] *= f[j];
#pragma unroll
        for (int nt = 0; nt < 4; nt++)
#pragma unroll
            for (int j = 0; j < 4; j++)
                Pl[w][lg * 4 + j][nt * 16 + lc] = (bf16)p[nt][j];
#pragma unroll
        for (int ks = 0; ks < 2; ks++) {
            bf16x8 aP = *(const bf16x8*)(&Pl[w][lc][ks * 32 + lg * 8]);
#pragma unroll
            for (int n = 0; n < 8; n++) {
                bf16x8 bV = *(const bf16x8*)(Vs + (n * 16 + lc) * 64 + (((ks * 4 + lg) ^ swz) * 8));
                acc[n] = __builtin_amdgcn_mfma_f32_16x16x32_bf16(aP, bV, acc[n], 0, 0, 0);
            }
        }
    }
#pragma unroll
    for (int j = 0; j < 4; j++) {
        float inv = 1.0f / lsum[j];
        int r = qt * 64 + w * 16 + lg * 4 + j;
#pragma unroll
        for (int n = 0; n < 8; n++) {
            float v = acc[n][j] * inv;
            cv[((size_t)(b * Sc + r) * Hc + h) * VDc + n * 16 + lc] = (bf16)v;
        }
    }
}

// ---------------- launch ----------------
extern "C" void kernel_launch(void* const* d_in, const int* in_sizes, int n_in,
                              void* d_out, int out_size, void* d_ws, size_t ws_size,
                              hipStream_t stream) {
    const float* x  = (const float*)d_in[0];
    const float* Wq = (const float*)d_in[1];
    const float* Wk = (const float*)d_in[2];
    const float* Wv = (const float*)d_in[3];
    const float* Wo = (const float*)d_in[4];
    const float* bo = (const float*)d_in[5];
    float* out = (float*)d_out;
    char* ws = (char*)d_ws;

    // workspace layout (bytes)
    bf16*  wcat = (bf16*)(ws + 0);           // 8192x2048 bf16 = 33554432
    bf16*  woT  = (bf16*)(ws + 33554432);    // 2048x2048 bf16 =  8388608
    bf16*  xb   = (bf16*)(ws + 41943040);    // 2048x2048 bf16 =  8388608
    bf16*  qkvb = (bf16*)(ws + 50331648);    // 2048x8192 bf16 = 33554432
    bf16*  cvb  = (bf16*)(ws + 83886080);    // 2048x2048 bf16 =  8388608
    bf16*  vTb  = (bf16*)(ws + 92274688);    // 32x128x1024 bf16 = 8388608
    float* cosT = (float*)(ws + 100663296);  // 1024x32 f32    =   131072
    float* sinT = (float*)(ws + 100794368);  // 1024x32 f32    =   131072

    k_cvt<<<2048, 256, 0, stream>>>(x, xb);
    k_transpose<<<dim3(32, 48), 256, 0, stream>>>(Wq, wcat, 3072);
    k_transpose<<<dim3(32, 48), 256, 0, stream>>>(Wk, wcat + (size_t)3072 * 2048, 3072);
    k_transpose<<<dim3(32, 32), 256, 0, stream>>>(Wv, wcat + (size_t)6144 * 2048, 2048);
    k_transpose<<<dim3(32, 32), 256, 0, stream>>>(Wo, woT, 2048);
    k_ropetab<<<128, 256, 0, stream>>>(cosT, sinT);
    // fused QKV projection: (2048x2048) x (8192x2048)^T -> (2048x8192) bf16, 256^2 tiles
    k_gemm8<<<256, 512, 0, stream>>>(xb, wcat, qkvb, NCAT, DIMc, NCAT / 256);
    k_rope<<<1024, 256, 0, stream>>>(qkvb, cosT, sinT, 0);     // Q section
    k_rope<<<1024, 256, 0, stream>>>(qkvb, cosT, sinT, NQ);    // K section
    k_vt<<<dim3(16, 2, 32), 256, 0, stream>>>(qkvb, vTb);      // V^T for PV B-frags
    k_attn<<<512, 256, 0, stream>>>(qkvb, vTb, cvb);
    // output projection with bias: (2048x2048) x (2048x2048)^T -> fp32 out
    k_gemm<false, true><<<256, 256, 0, stream>>>(cvb, woT, out, bo, DIMc, DIMc);
}

// Round 5
// 176.987 us; speedup vs baseline: 1.8681x; 1.1753x over previous
//
#include <hip/hip_runtime.h>

// MLA forward: out = softmax_causal( rope(x@Wq) @ rope(x@Wk)^T / sqrt(192) ) @ (x@Wv) @ Wo + bo
// bf16 MFMA everywhere (threshold is 2% of max|ref|), fp32 accumulation.
// R5: out-projection -> 128x128 8-wave phase-pipelined GEMM (same T2/T4/T5 discipline as k_gemm8);
//     transpose x4 and rope x2 launches fused.

typedef __bf16 bf16;
typedef __bf16 bf16x8 __attribute__((ext_vector_type(8)));
typedef __bf16 bf16x4 __attribute__((ext_vector_type(4)));
typedef float  f32x4  __attribute__((ext_vector_type(4)));

#define DEVI __device__ __forceinline__

static constexpr int Bc = 2, Sc = 1024, DIMc = 2048, Hc = 16;
static constexpr int NOPEc = 128, QKDc = 192, VDc = 128;
static constexpr int NQ    = Hc * QKDc;        // 3072
static constexpr int NCAT  = NQ + NQ + Hc*VDc; // 8192  [Q | K | V] per row

// ---------------- fp32 -> bf16 convert (vectorized) ----------------
__global__ __launch_bounds__(256) void k_cvt(const float* __restrict__ in, bf16* __restrict__ out) {
    int i = (blockIdx.x * 256 + threadIdx.x) * 8;
    float4 a = *(const float4*)(in + i);
    float4 b = *(const float4*)(in + i + 4);
    bf16x8 o;
    o[0]=(bf16)a.x; o[1]=(bf16)a.y; o[2]=(bf16)a.z; o[3]=(bf16)a.w;
    o[4]=(bf16)b.x; o[5]=(bf16)b.y; o[6]=(bf16)b.z; o[7]=(bf16)b.w;
    *(bf16x8*)(out + i) = o;
}

// ---------------- fused transpose+convert of all 4 weights ----------------
// in (K=2048 x N) fp32 -> out (N x 2048) bf16; segmented over y-tiles.
__global__ __launch_bounds__(256) void k_transpose_all(const float* __restrict__ Wq, const float* __restrict__ Wk,
                                                       const float* __restrict__ Wv, const float* __restrict__ Wo,
                                                       bf16* __restrict__ wcat, bf16* __restrict__ woT) {
    __shared__ float tile[64][68];
    int yt = blockIdx.y;
    const float* src; bf16* dst; int N, n0;
    if (yt < 48)       { src = Wq; N = 3072; n0 = yt * 64;         dst = wcat; }
    else if (yt < 96)  { src = Wk; N = 3072; n0 = (yt - 48) * 64;  dst = wcat + (size_t)3072 * 2048; }
    else if (yt < 128) { src = Wv; N = 2048; n0 = (yt - 96) * 64;  dst = wcat + (size_t)6144 * 2048; }
    else               { src = Wo; N = 2048; n0 = (yt - 128) * 64; dst = woT; }
    int k0 = blockIdx.x * 64;
    int tr = threadIdx.x >> 4, tc = (threadIdx.x & 15) * 4;
#pragma unroll
    for (int i = 0; i < 4; i++) {
        int r = tr + i * 16;
        float4 v = *(const float4*)(src + (size_t)(k0 + r) * N + n0 + tc);
        tile[r][tc+0] = v.x; tile[r][tc+1] = v.y; tile[r][tc+2] = v.z; tile[r][tc+3] = v.w;
    }
    __syncthreads();
#pragma unroll
    for (int i = 0; i < 4; i++) {
        int n = tr + i * 16;
        bf16x4 o;
#pragma unroll
        for (int j = 0; j < 4; j++) o[j] = (bf16)tile[tc + j][n];
        *(bf16x4*)(dst + (size_t)(n0 + n) * 2048 + k0 + tc) = o;
    }
}

// ---------------- V^T: qkvb V-section (s-major) -> vT[bh][vd][s] ----------------
__global__ __launch_bounds__(256) void k_vt(const bf16* __restrict__ qkv, bf16* __restrict__ vT) {
    int st = blockIdx.x, dt = blockIdx.y, bh = blockIdx.z;
    int b = bh >> 4, h = bh & 15;
    __shared__ bf16 tile[64][72];
    int r = threadIdx.x >> 3, c8 = (threadIdx.x & 7) * 8;
    const bf16* src = qkv + (size_t)(b * Sc + st * 64) * NCAT + 2 * NQ + h * VDc + dt * 64;
#pragma unroll
    for (int i = 0; i < 2; i++) {
        int rr = r + i * 32;   // s_local
        *(bf16x8*)&tile[rr][c8] = *(const bf16x8*)(src + (size_t)rr * NCAT + c8);
    }
    __syncthreads();
    bf16* dst = vT + ((size_t)bh * 128 + dt * 64) * Sc + st * 64;
#pragma unroll
    for (int i = 0; i < 2; i++) {
        int rr = r + i * 32;   // vd_local
        bf16x8 o;
#pragma unroll
        for (int j = 0; j < 8; j++) o[j] = tile[c8 + j][rr];
        *(bf16x8*)(dst + (size_t)rr * Sc + c8) = o;
    }
}

// ---------------- RoPE cos/sin table: [S][32] each ----------------
__global__ void k_ropetab(float* __restrict__ cosT, float* __restrict__ sinT) {
    int idx = blockIdx.x * 256 + threadIdx.x;  // S*32 = 32768
    int pos = idx >> 5, i = idx & 31;
    float theta = expf(-(float)i * (9.210340371976184f / 32.0f)); // 10000^(-i/32)
    float ang = (float)pos * theta;
    cosT[idx] = cosf(ang);
    sinT[idx] = sinf(ang);
}

// ---------------- RoPE apply in-place on bf16 QKV rows (Q and K sections in one launch) ----------------
__global__ __launch_bounds__(256) void k_rope2(bf16* __restrict__ qkv, const float* __restrict__ cosT,
                                               const float* __restrict__ sinT) {
    int bidx = blockIdx.x;
    int secbase = (bidx >= 1024) ? NQ : 0;
    int idx = (bidx & 1023) * 256 + threadIdx.x;  // B*S*H*8 = 262144 per section
    int g = idx & 7, h = (idx >> 3) & 15, row = idx >> 7;
    int s = row & (Sc - 1);
    bf16* p = qkv + (size_t)row * NCAT + secbase + h * QKDc + NOPEc + g * 8;
    bf16x8 v = *(bf16x8*)p;
    const float* cp = cosT + s * 32 + g * 4;
    const float* sp = sinT + s * 32 + g * 4;
#pragma unroll
    for (int q = 0; q < 4; q++) {
        float x0 = (float)v[2*q], x1 = (float)v[2*q+1];
        float c = cp[q], sn = sp[q];
        v[2*q]   = (bf16)(x0 * c - x1 * sn);
        v[2*q+1] = (bf16)(x1 * c + x0 * sn);
    }
    *(bf16x8*)p = v;
}

// ---------------- async global->LDS, 16B per lane ----------------
DEVI void gload16(const bf16* g, bf16* l) {
    __builtin_amdgcn_global_load_lds((const __attribute__((address_space(1))) void*)g,
                                     (__attribute__((address_space(3))) void*)l, 16, 0, 0);
}

// ================= 256x256 multi-phase GEMM (QKV projection) =================
// C = A(MxK) * Bt(NxK)^T, bf16 out. 512 threads, 8 waves (2x4), dbuf 128 KiB LDS.
// 4 phases/K-tile(64); counted vmcnt(4); setprio around MFMA; XOR-swizzled LDS (0 conflicts, R4-measured).
__global__ __launch_bounds__(512, 2) void k_gemm8(const bf16* __restrict__ A, const bf16* __restrict__ Bt,
                                                  bf16* __restrict__ C, int N, int K, int NCT) {
    __shared__ __align__(16) bf16 lds[2][2][2][256 * 32];  // [buf][A=0/B=1][ks][slice] = 128 KiB
    const int tid = threadIdx.x;
    const int l = tid & 63, wid = tid >> 6;
    const int lg = l >> 4, lc = l & 15;
    const int wm = wid >> 2, wn = wid & 3;          // 2x4 wave grid; wave owns 128x64
    const int bid = blockIdx.x;
    const int xcd = bid & 7, g = bid >> 3;
    const int per = NCT >> 3;                        // col-panels per XCD
    const int rt = g & 7, ct = xcd * per + (g >> 3); // 8 row-tiles, panels pinned to XCD
    const int row0 = rt * 256, col0 = ct * 256;
    const int NT = K >> 6;

    const bf16* Abase = A  + (size_t)row0 * K;
    const bf16* Bbase = Bt + (size_t)col0 * K;

    size_t srcoff0, srcoff1;
    int ldsoff0, ldsoff1;
    {
        int li0 = tid,        r0 = li0 >> 2, u0 = li0 & 3;
        int li1 = 512 + tid,  r1 = li1 >> 2, u1 = li1 & 3;
        srcoff0 = (size_t)r0 * K + ((u0 ^ ((r0 >> 1) & 3)) << 3);  ldsoff0 = li0 * 8;
        srcoff1 = (size_t)r1 * K + ((u1 ^ ((r1 >> 1) & 3)) << 3);  ldsoff1 = li1 * 8;
    }

#define STAGE8(ab, ks, ktile, buf) { \
    const bf16* gb_ = ((ab) ? Bbase : Abase) + (ktile) * 64 + (ks) * 32; \
    bf16* lb_ = &lds[buf][ab][ks][0]; \
    gload16(gb_ + srcoff0, lb_ + ldsoff0); \
    gload16(gb_ + srcoff1, lb_ + ldsoff1); }

    f32x4 acc[8][4] = {};

    STAGE8(0, 0, 0, 0); STAGE8(1, 0, 0, 0); STAGE8(0, 1, 0, 0); STAGE8(1, 1, 0, 0);
    asm volatile("s_waitcnt vmcnt(4)" ::: "memory");
    __builtin_amdgcn_s_barrier();
    asm volatile("" ::: "memory");

    for (int kt = 0; kt < NT; ++kt) {
        const int cur = kt & 1, nxt = cur ^ 1;
        const bool notlast = (kt + 1 < NT);
        bf16x8 aF[4], bB[4];
#pragma unroll
        for (int ph = 0; ph < 4; ph++) {
            const int ks = ph >> 1, mh = ph & 1;
            const bf16* As_ = &lds[cur][0][ks][0];
            const bf16* Bs_ = &lds[cur][1][ks][0];
            if (mh == 0) {
#pragma unroll
                for (int fc = 0; fc < 4; fc++) {
                    int row = wn * 64 + fc * 16 + lc;
                    bB[fc] = *(const bf16x8*)(Bs_ + row * 32 + ((lg ^ ((row >> 1) & 3)) << 3));
                }
            }
#pragma unroll
            for (int i = 0; i < 4; i++) {
                int row = wm * 128 + (mh * 4 + i) * 16 + lc;
                aF[i] = *(const bf16x8*)(As_ + row * 32 + ((lg ^ ((row >> 1) & 3)) << 3));
            }
            if (notlast) {
                if      (ph == 0) STAGE8(0, 0, kt + 1, nxt)
                else if (ph == 1) STAGE8(1, 0, kt + 1, nxt)
                else if (ph == 2) STAGE8(0, 1, kt + 1, nxt)
                else              STAGE8(1, 1, kt + 1, nxt)
            }
            __builtin_amdgcn_s_barrier();
            asm volatile("" ::: "memory");
            __builtin_amdgcn_s_setprio(1);
#pragma unroll
            for (int i = 0; i < 4; i++)
#pragma unroll
                for (int fc = 0; fc < 4; fc++)
                    acc[mh * 4 + i][fc] =
                        __builtin_amdgcn_mfma_f32_16x16x32_bf16(aF[i], bB[fc], acc[mh * 4 + i][fc], 0, 0, 0);
            __builtin_amdgcn_s_setprio(0);
            if (ph == 1) {
                if (notlast) asm volatile("s_waitcnt vmcnt(4)" ::: "memory");
                else         asm volatile("s_waitcnt vmcnt(0)" ::: "memory");
            }
            if (ph == 3 && notlast) {
                asm volatile("s_waitcnt vmcnt(4)" ::: "memory");
            }
            __builtin_amdgcn_s_barrier();
            asm volatile("" ::: "memory");
        }
    }
#undef STAGE8
#pragma unroll
    for (int m = 0; m < 8; m++)
#pragma unroll
        for (int fc = 0; fc < 4; fc++)
#pragma unroll
            for (int j = 0; j < 4; j++) {
                int r = row0 + wm * 128 + m * 16 + lg * 4 + j;
                int c = col0 + wn * 64 + fc * 16 + lc;
                C[(size_t)r * N + c] = (bf16)acc[m][fc][j];
            }
}

// ================= 128x128 8-wave phase-pipelined GEMM (out-projection, fp32 out + bias) =================
// M=2048, N=2048, K=2048: grid 16x16 = 256 blocks (bijective XCD pinning), 512 threads,
// wave owns 64x32, dbuf 64 KiB LDS, 2 phases/K-tile (8 MFMA each), vmcnt(2) counted waits.
__global__ __launch_bounds__(512, 2) void k_gemmO(const bf16* __restrict__ A, const bf16* __restrict__ Bt,
                                                  float* __restrict__ C, const float* __restrict__ bias,
                                                  int N, int K) {
    __shared__ __align__(16) bf16 lds[2][2][2][128 * 32];  // [buf][A/B][ks][slice] = 64 KiB
    const int tid = threadIdx.x;
    const int l = tid & 63, wid = tid >> 6;
    const int lg = l >> 4, lc = l & 15;
    const int wm = wid >> 2, wn = wid & 3;          // 2x4 wave grid; wave owns 64x32
    const int bid = blockIdx.x;
    const int xcd = bid & 7, g = bid >> 3;
    const int rt = g & 15, ct = xcd * 2 + (g >> 4); // 16 row-tiles, 2 col-panels per XCD
    const int row0 = rt * 128, col0 = ct * 128;
    const int NT = K >> 6;

    const bf16* Abase = A  + (size_t)row0 * K;
    const bf16* Bbase = Bt + (size_t)col0 * K;

    size_t srcoff; int ldsoff;
    {
        int r0 = tid >> 2, u0 = tid & 3;
        srcoff = (size_t)r0 * K + ((u0 ^ ((r0 >> 1) & 3)) << 3);
        ldsoff = tid * 8;
    }

#define STAGEO(ab, ks, ktile, buf) { \
    const bf16* gb_ = ((ab) ? Bbase : Abase) + (ktile) * 64 + (ks) * 32; \
    gload16(gb_ + srcoff, &lds[buf][ab][ks][0] + ldsoff); }

    f32x4 acc[4][2] = {};

    // prologue: tile 0 -> buf 0 (A0, B0, A1, B1 = 4 loads/thread)
    STAGEO(0, 0, 0, 0); STAGEO(1, 0, 0, 0); STAGEO(0, 1, 0, 0); STAGEO(1, 1, 0, 0);
    asm volatile("s_waitcnt vmcnt(2)" ::: "memory");   // ks0 landed; ks1 in flight
    __builtin_amdgcn_s_barrier();
    asm volatile("" ::: "memory");

    for (int kt = 0; kt < NT; ++kt) {
        const int cur = kt & 1, nxt = cur ^ 1;
        const bool notlast = (kt + 1 < NT);
#pragma unroll
        for (int ph = 0; ph < 2; ph++) {
            const bf16* As_ = &lds[cur][0][ph][0];
            const bf16* Bs_ = &lds[cur][1][ph][0];
            bf16x8 aF[4], bB[2];
#pragma unroll
            for (int n = 0; n < 2; n++) {
                int row = wn * 32 + n * 16 + lc;
                bB[n] = *(const bf16x8*)(Bs_ + row * 32 + ((lg ^ ((row >> 1) & 3)) << 3));
            }
#pragma unroll
            for (int m = 0; m < 4; m++) {
                int row = wm * 64 + m * 16 + lc;
                aF[m] = *(const bf16x8*)(As_ + row * 32 + ((lg ^ ((row >> 1) & 3)) << 3));
            }
            if (notlast) {
                if (ph == 0) { STAGEO(0, 0, kt + 1, nxt); STAGEO(1, 0, kt + 1, nxt); }
                else         { STAGEO(0, 1, kt + 1, nxt); STAGEO(1, 1, kt + 1, nxt); }
            }
            __builtin_amdgcn_s_barrier();
            asm volatile("" ::: "memory");
            __builtin_amdgcn_s_setprio(1);
#pragma unroll
            for (int m = 0; m < 4; m++)
#pragma unroll
                for (int n = 0; n < 2; n++)
                    acc[m][n] = __builtin_amdgcn_mfma_f32_16x16x32_bf16(aF[m], bB[n], acc[m][n], 0, 0, 0);
            __builtin_amdgcn_s_setprio(0);
            // queue: 2 loads/phase; wait for the pair needed 1 phase ahead (staged 2 phases ago)
            if (notlast)          asm volatile("s_waitcnt vmcnt(2)" ::: "memory");
            else if (ph == 0)     asm volatile("s_waitcnt vmcnt(0)" ::: "memory");
            __builtin_amdgcn_s_barrier();
            asm volatile("" ::: "memory");
        }
    }
#undef STAGEO
    // epilogue: fp32 + bias
#pragma unroll
    for (int m = 0; m < 4; m++)
#pragma unroll
        for (int n = 0; n < 2; n++)
#pragma unroll
            for (int j = 0; j < 4; j++) {
                int r = row0 + wm * 64 + m * 16 + lg * 4 + j;
                int c = col0 + wn * 32 + n * 16 + lc;
                C[(size_t)r * N + c] = acc[m][n][j] + bias[c];
            }
}

// ---------------- flash attention: K/V cooperatively LDS-staged, pipelined ----------------
__global__ __launch_bounds__(256, 3) void k_attn(const bf16* __restrict__ qkv, const bf16* __restrict__ vT,
                                                 bf16* __restrict__ cv) {
    const int bid = blockIdx.x;
    const int xcd = bid & 7, g = bid >> 3;
    const int qt = 15 - (g & 15);          // heavy q-tiles dispatched first (LPT)
    const int bh = xcd + 8 * (g >> 4);     // all q-tiles of a bh pinned to one XCD
    const int b = bh >> 4, h = bh & 15;
    const int tid = threadIdx.x, l = tid & 63, w = tid >> 6;
    const int lg = l >> 4, lc = l & 15;
    __shared__ __align__(16) bf16 Ks[64 * 192];     // 24576 B
    __shared__ __align__(16) bf16 Vs[128 * 64];     // 16384 B
    __shared__ __align__(16) bf16 Pl[4][16][72];    //  9216 B
    const bf16* Qb = qkv + (size_t)b * Sc * NCAT + h * QKDc;
    const bf16* Kb = Qb + NQ;
    const bf16* Vt = vT + (size_t)bh * 128 * Sc;    // [128][1024]

    int sK[6];
#pragma unroll
    for (int r = 0; r < 6; r++) {
        int li = r * 256 + tid;
        int row = li / 24, c16 = li - row * 24;
        sK[r] = row * NCAT + ((c16 ^ (row & 7)) * 8);
    }
    int sV[4];
#pragma unroll
    for (int r = 0; r < 4; r++) {
        int li = r * 256 + tid;
        int row = li >> 3, c16 = li & 7;
        sV[r] = row * Sc + ((c16 ^ (row & 7)) * 8);
    }
    const int swz = lc & 7;

    bf16x8 qF[6];
    const int qrow = qt * 64 + w * 16 + lc;
#pragma unroll
    for (int kc = 0; kc < 6; kc++) qF[kc] = *(const bf16x8*)(Qb + (size_t)qrow * NCAT + kc * 32 + lg * 8);

    f32x4 acc[8] = {};
    float mrow[4] = {-1e30f, -1e30f, -1e30f, -1e30f};
    float lsum[4] = {0.f, 0.f, 0.f, 0.f};
    const float scale = 0.07216878364870323f;  // 192^-0.5

#pragma unroll
    for (int r = 0; r < 6; r++) gload16(Kb + sK[r], Ks + (r * 256 + tid) * 8);

    for (int c = 0; c <= qt; ++c) {
        const int t0 = c * 64;
        __syncthreads();   // B1: drains vmcnt -> K[c] staged
#pragma unroll
        for (int r = 0; r < 4; r++) gload16(Vt + t0 + sV[r], Vs + (r * 256 + tid) * 8);
        f32x4 sc[4] = {};
#pragma unroll
        for (int nt = 0; nt < 4; nt++)
#pragma unroll
            for (int kc = 0; kc < 6; kc++) {
                bf16x8 kf = *(const bf16x8*)(Ks + (nt * 16 + lc) * 192 + (((kc * 4 + lg) ^ swz) * 8));
                sc[nt] = __builtin_amdgcn_mfma_f32_16x16x32_bf16(qF[kc], kf, sc[nt], 0, 0, 0);
            }
        __syncthreads();   // B2: K[c] reads done; drains vmcnt -> V[c] staged
        if (c < qt) {
#pragma unroll
            for (int r = 0; r < 6; r++) gload16(Kb + (size_t)(t0 + 64) * NCAT + sK[r], Ks + (r * 256 + tid) * 8);
        }
        float p[4][4];
        float cmax[4] = {-1e30f, -1e30f, -1e30f, -1e30f};
        const bool diag = (c == qt);
#pragma unroll
        for (int nt = 0; nt < 4; nt++)
#pragma unroll
            for (int j = 0; j < 4; j++) {
                float v = sc[nt][j] * scale;
                if (diag) {
                    int tg = t0 + nt * 16 + lc;
                    int rg = qt * 64 + w * 16 + lg * 4 + j;
                    if (tg > rg) v = -1e9f;
                }
                p[nt][j] = v;
                cmax[j] = fmaxf(cmax[j], v);
            }
#pragma unroll
        for (int j = 0; j < 4; j++)
#pragma unroll
            for (int d = 1; d < 16; d <<= 1) cmax[j] = fmaxf(cmax[j], __shfl_xor(cmax[j], d));
        float f[4];
#pragma unroll
        for (int j = 0; j < 4; j++) {
            float nm = fmaxf(mrow[j], cmax[j]);
            f[j] = __expf(mrow[j] - nm);
            mrow[j] = nm;
        }
        float psum[4] = {0.f, 0.f, 0.f, 0.f};
#pragma unroll
        for (int nt = 0; nt < 4; nt++)
#pragma unroll
            for (int j = 0; j < 4; j++) {
                p[nt][j] = __expf(p[nt][j] - mrow[j]);
                psum[j] += p[nt][j];
            }
#pragma unroll
        for (int j = 0; j < 4; j++) {
#pragma unroll
            for (int d = 1; d < 16; d <<= 1) psum[j] += __shfl_xor(psum[j], d);
            lsum[j] = lsum[j] * f[j] + psum[j];
        }
#pragma unroll
        for (int n = 0; n < 8; n++)
#pragma unroll
            for (int j = 0; j < 4; j++) acc[n][j] *= f[j];
#pragma unroll
        for (int nt = 0; nt < 4; nt++)
#pragma unroll
            for (int j = 0; j < 4; j++)
                Pl[w][lg * 4 + j][nt * 16 + lc] = (bf16)p[nt][j];
#pragma unroll
        for (int ks = 0; ks < 2; ks++) {
            bf16x8 aP = *(const bf16x8*)(&Pl[w][lc][ks * 32 + lg * 8]);
#pragma unroll
            for (int n = 0; n < 8; n++) {
                bf16x8 bV = *(const bf16x8*)(Vs + (n * 16 + lc) * 64 + (((ks * 4 + lg) ^ swz) * 8));
                acc[n] = __builtin_amdgcn_mfma_f32_16x16x32_bf16(aP, bV, acc[n], 0, 0, 0);
            }
        }
    }
#pragma unroll
    for (int j = 0; j < 4; j++) {
        float inv = 1.0f / lsum[j];
        int r = qt * 64 + w * 16 + lg * 4 + j;
#pragma unroll
        for (int n = 0; n < 8; n++) {
            float v = acc[n][j] * inv;
            cv[((size_t)(b * Sc + r) * Hc + h) * VDc + n * 16 + lc] = (bf16)v;
        }
    }
}

// ---------------- launch ----------------
extern "C" void kernel_launch(void* const* d_in, const int* in_sizes, int n_in,
                              void* d_out, int out_size, void* d_ws, size_t ws_size,
                              hipStream_t stream) {
    const float* x  = (const float*)d_in[0];
    const float* Wq = (const float*)d_in[1];
    const float* Wk = (const float*)d_in[2];
    const float* Wv = (const float*)d_in[3];
    const float* Wo = (const float*)d_in[4];
    const float* bo = (const float*)d_in[5];
    float* out = (float*)d_out;
    char* ws = (char*)d_ws;

    // workspace layout (bytes)
    bf16*  wcat = (bf16*)(ws + 0);           // 8192x2048 bf16 = 33554432
    bf16*  woT  = (bf16*)(ws + 33554432);    // 2048x2048 bf16 =  8388608
    bf16*  xb   = (bf16*)(ws + 41943040);    // 2048x2048 bf16 =  8388608
    bf16*  qkvb = (bf16*)(ws + 50331648);    // 2048x8192 bf16 = 33554432
    bf16*  cvb  = (bf16*)(ws + 83886080);    // 2048x2048 bf16 =  8388608
    bf16*  vTb  = (bf16*)(ws + 92274688);    // 32x128x1024 bf16 = 8388608
    float* cosT = (float*)(ws + 100663296);  // 1024x32 f32    =   131072
    float* sinT = (float*)(ws + 100794368);  // 1024x32 f32    =   131072

    k_cvt<<<2048, 256, 0, stream>>>(x, xb);
    k_transpose_all<<<dim3(32, 160), 256, 0, stream>>>(Wq, Wk, Wv, Wo, wcat, woT);
    k_ropetab<<<128, 256, 0, stream>>>(cosT, sinT);
    // fused QKV projection: (2048x2048) x (8192x2048)^T -> (2048x8192) bf16, 256^2 tiles
    k_gemm8<<<256, 512, 0, stream>>>(xb, wcat, qkvb, NCAT, DIMc, NCAT / 256);
    k_rope2<<<2048, 256, 0, stream>>>(qkvb, cosT, sinT);       // Q + K sections
    k_vt<<<dim3(16, 2, 32), 256, 0, stream>>>(qkvb, vTb);      // V^T for PV B-frags
    k_attn<<<512, 256, 0, stream>>>(qkvb, vTb, cvb);
    // output projection with bias: (2048x2048) x (2048x2048)^T -> fp32 out, 128^2 8-wave tiles
    k_gemmO<<<256, 512, 0, stream>>>(cvb, woT, out, bo, DIMc, DIMc);
}